// Round 15
// baseline (278.064 us; speedup 1.0000x reference)
//
#include <hip/hip_runtime.h>
#include <cstdint>
#include <cstddef>

#define V 100000
#define H 128
#define B 2048
#define NT 6250      // vocab tiles of 16 (V/16 exact)
#define CHUNK 14     // tiles per strip (even -> aligned 128B tile pairs)
#define NSTRIP 447   // 447*14 = 6258 >= 6250; last strip = 6 tiles (even)
#define NRG 8        // row-groups: 8 * 256 rows = 2048
#define PREPB ((B * H + 255) / 256)   // 1024 blocks for prep part

typedef __attribute__((ext_vector_type(8))) short short8;
typedef __attribute__((ext_vector_type(4))) float f32x4;

static __device__ __forceinline__ unsigned short f2bf(float f) {
  unsigned int u = __builtin_bit_cast(unsigned int, f);
  u += 0x7fffu + ((u >> 16) & 1u);   // round-to-nearest-even
  return (unsigned short)(u >> 16);
}

// ---- fused prep: blocks [0, castBlocks) pack W_dec -> bf16 fragments;
//      blocks [castBlocks, castBlocks+PREPB) build hidden + zero accum. ----
// Wpk[t*2048 + s*512 + lane*8 + j] = bf16( W[(t*16+(lane&15))*H + (lane>>4)*8 + s*32 + j] )
__global__ void __launch_bounds__(256) prep_fused(
    const int* __restrict__ idx, const float* __restrict__ W_enc,
    const float* __restrict__ b_enc, const float* __restrict__ W_dec,
    unsigned short* __restrict__ hid, float* __restrict__ accum,
    unsigned short* __restrict__ Wpk, int castBlocks) {
  const int bid = blockIdx.x;
  if (bid < castBlocks) {
    const int t = bid;                      // vocab tile
    const int s = threadIdx.x >> 6;         // k-slice 0..3
    const int lane = threadIdx.x & 63;
    const int l15 = lane & 15;
    const int q = lane >> 4;
    const float* p = W_dec + (size_t)(t * 16 + l15) * H + q * 8 + s * 32;
    float4 x = *reinterpret_cast<const float4*>(p);
    float4 y = *reinterpret_cast<const float4*>(p + 4);
    short8 o;
    o[0] = (short)f2bf(x.x); o[1] = (short)f2bf(x.y);
    o[2] = (short)f2bf(x.z); o[3] = (short)f2bf(x.w);
    o[4] = (short)f2bf(y.x); o[5] = (short)f2bf(y.y);
    o[6] = (short)f2bf(y.z); o[7] = (short)f2bf(y.w);
    *reinterpret_cast<short8*>(Wpk + (size_t)t * 2048 + s * 512 + lane * 8) = o;
  } else {
    const int gid = (bid - castBlocks) * 256 + threadIdx.x;
    if (gid < B) accum[gid] = 0.0f;
    if (gid >= B * H) return;
    const int b = gid >> 7;
    const int k = gid & (H - 1);
    float v = W_enc[(size_t)k * V + idx[b]] + b_enc[k];
    hid[gid] = f2bf(v);
  }
}

// ---- W-fragment loader: packed-bf16 path or fp32 scattered fallback ----
template <bool PRE>
static __device__ __forceinline__ short8 loadW(const void* Wv, int t, int s,
                                               int lane, int l15, int q) {
  if constexpr (PRE) {
    return *reinterpret_cast<const short8*>(
        reinterpret_cast<const unsigned short*>(Wv) +
        (size_t)t * 2048 + s * 512 + lane * 8);
  } else {
    const float* p = reinterpret_cast<const float*>(Wv) +
                     (size_t)(t * 16 + l15) * H + q * 8 + s * 32;
    float4 x = *reinterpret_cast<const float4*>(p);
    float4 y = *reinterpret_cast<const float4*>(p + 4);
    short8 o;
    o[0] = (short)f2bf(x.x); o[1] = (short)f2bf(x.y);
    o[2] = (short)f2bf(x.z); o[3] = (short)f2bf(x.w);
    o[4] = (short)f2bf(y.x); o[5] = (short)f2bf(y.y);
    o[6] = (short)f2bf(y.z); o[7] = (short)f2bf(y.w);
    return o;
  }
}

// SWAPPED operands: A = W fragment (vocab = M), B = hid fragment (batch = N).
// A/B in-layout: row|col = l15, k = q*8+j. D: row(vocab) = q*4+j, col(batch) = l15.

// ---- pass A (r9 body): per-row sum of exp(logit), depth-1 prefetch ----
template <bool PRE>
__global__ void __launch_bounds__(256) lse_pass(
    const void* __restrict__ Wv, const unsigned short* __restrict__ hid,
    const float* __restrict__ b_dec, float* __restrict__ accum) {
  const int lane = threadIdx.x & 63;
  const int wv = threadIdx.x >> 6;
  const int l15 = lane & 15;
  const int q = lane >> 4;
  const int rowbase = blockIdx.y * 256 + wv * 64;  // 64 batch rows per wave

  const unsigned short* ap = hid + (size_t)(rowbase + l15) * H + q * 8;
  short8 hf[4][4];
#pragma unroll
  for (int f = 0; f < 4; ++f)
#pragma unroll
    for (int s = 0; s < 4; ++s)
      hf[f][s] = *reinterpret_cast<const short8*>(ap + (size_t)f * 16 * H + s * 32);

  float ps[4] = {0.f, 0.f, 0.f, 0.f};

  const int t0 = blockIdx.x * CHUNK;
  const int t1 = (t0 + CHUNK < NT) ? t0 + CHUNK : NT;

  short8 wb[4];
#pragma unroll
  for (int s = 0; s < 4; ++s) wb[s] = loadW<PRE>(Wv, t0, s, lane, l15, q);
  float4 bd4 = *reinterpret_cast<const float4*>(b_dec + t0 * 16 + q * 4);

#pragma unroll 2
  for (int t = t0; t < t1; ++t) {
    const int tn = (t + 1 < t1) ? t + 1 : t;
    short8 wn[4];
#pragma unroll
    for (int s = 0; s < 4; ++s) wn[s] = loadW<PRE>(Wv, tn, s, lane, l15, q);
    float4 bdn = *reinterpret_cast<const float4*>(b_dec + tn * 16 + q * 4);

#pragma unroll
    for (int f = 0; f < 4; ++f) {
      f32x4 acc = {0.f, 0.f, 0.f, 0.f};
#pragma unroll
      for (int s = 0; s < 4; ++s)
        acc = __builtin_amdgcn_mfma_f32_16x16x32_bf16(wb[s], hf[f][s], acc, 0, 0, 0);
      ps[f] += __expf(acc[0] + bd4.x) + __expf(acc[1] + bd4.y) +
               __expf(acc[2] + bd4.z) + __expf(acc[3] + bd4.w);
    }
#pragma unroll
    for (int s = 0; s < 4; ++s) wb[s] = wn[s];
    bd4 = bdn;
  }

#pragma unroll
  for (int f = 0; f < 4; ++f) {
    ps[f] += __shfl_xor(ps[f], 16, 64);
    ps[f] += __shfl_xor(ps[f], 32, 64);
    if (q == 0) atomicAdd(&accum[rowbase + f * 16 + l15], ps[f]);
  }
}

// ---- pass B (r9 body): recompute logits, write out = logit + b_dec - lse.
// Tile-pair processing: two 64B halves of one 128B line stored back-to-back
// (plain stores) so L2 merges full lines. ----
template <bool PRE>
__global__ void __launch_bounds__(256) out_pass(
    const void* __restrict__ Wv, const unsigned short* __restrict__ hid,
    const float* __restrict__ b_dec, const float* __restrict__ accum,
    float* __restrict__ out) {
  const int lane = threadIdx.x & 63;
  const int wv = threadIdx.x >> 6;
  const int l15 = lane & 15;
  const int q = lane >> 4;
  const int rowbase = blockIdx.y * 256 + wv * 64;

  const unsigned short* ap = hid + (size_t)(rowbase + l15) * H + q * 8;
  short8 hf[4][4];
#pragma unroll
  for (int f = 0; f < 4; ++f)
#pragma unroll
    for (int s = 0; s < 4; ++s)
      hf[f][s] = *reinterpret_cast<const short8*>(ap + (size_t)f * 16 * H + s * 32);

  const int t0 = blockIdx.x * CHUNK;   // even -> (t0, t0+1) is a 128B line pair
  const int t1 = (t0 + CHUNK < NT) ? t0 + CHUNK : NT;
  const int NPAIR = (t1 - t0) >> 1;    // even counts everywhere

  float ls[4];
  size_t optr[4];
#pragma unroll
  for (int f = 0; f < 4; ++f) {
    ls[f] = __logf(accum[rowbase + f * 16 + l15]);
    optr[f] = (size_t)(rowbase + f * 16 + l15) * V + (size_t)t0 * 16 + q * 4;
  }

  // current pair fragments (a = even tile, b = odd tile)
  short8 wa[4], wbv[4];
#pragma unroll
  for (int s = 0; s < 4; ++s) {
    wa[s] = loadW<PRE>(Wv, t0, s, lane, l15, q);
    wbv[s] = loadW<PRE>(Wv, t0 + 1, s, lane, l15, q);
  }
  float4 bda = *reinterpret_cast<const float4*>(b_dec + t0 * 16 + q * 4);
  float4 bdb = *reinterpret_cast<const float4*>(b_dec + (t0 + 1) * 16 + q * 4);

  for (int tp = 0; tp < NPAIR; ++tp) {
    // prefetch next pair
    const int tpn = (tp + 1 < NPAIR) ? tp + 1 : tp;
    const int ta = t0 + 2 * tpn;
    short8 na[4], nb[4];
#pragma unroll
    for (int s = 0; s < 4; ++s) {
      na[s] = loadW<PRE>(Wv, ta, s, lane, l15, q);
      nb[s] = loadW<PRE>(Wv, ta + 1, s, lane, l15, q);
    }
    const float4 bna = *reinterpret_cast<const float4*>(b_dec + ta * 16 + q * 4);
    const float4 bnb = *reinterpret_cast<const float4*>(b_dec + (ta + 1) * 16 + q * 4);

#pragma unroll
    for (int f = 0; f < 4; ++f) {
      f32x4 acc0 = {0.f, 0.f, 0.f, 0.f};
      f32x4 acc1 = {0.f, 0.f, 0.f, 0.f};
#pragma unroll
      for (int s = 0; s < 4; ++s) {
        acc0 = __builtin_amdgcn_mfma_f32_16x16x32_bf16(wa[s], hf[f][s], acc0, 0, 0, 0);
        acc1 = __builtin_amdgcn_mfma_f32_16x16x32_bf16(wbv[s], hf[f][s], acc1, 0, 0, 0);
      }
      f32x4 o0, o1;
      o0[0] = acc0[0] + bda.x - ls[f];
      o0[1] = acc0[1] + bda.y - ls[f];
      o0[2] = acc0[2] + bda.z - ls[f];
      o0[3] = acc0[3] + bda.w - ls[f];
      o1[0] = acc1[0] + bdb.x - ls[f];
      o1[1] = acc1[1] + bdb.y - ls[f];
      o1[2] = acc1[2] + bdb.z - ls[f];
      o1[3] = acc1[3] + bdb.w - ls[f];
      // two halves of the same 128B line, issued back-to-back; plain stores
      float* p = out + optr[f];
      *reinterpret_cast<f32x4*>(p) = o0;
      *reinterpret_cast<f32x4*>(p + 16) = o1;
      optr[f] += 32;
    }
#pragma unroll
    for (int s = 0; s < 4; ++s) { wa[s] = na[s]; wbv[s] = nb[s]; }
    bda = bna;
    bdb = bnb;
  }
}

extern "C" void kernel_launch(void* const* d_in, const int* in_sizes, int n_in,
                              void* d_out, int out_size, void* d_ws, size_t ws_size,
                              hipStream_t stream) {
  const int* idx = (const int*)d_in[0];
  const float* W_enc = (const float*)d_in[1];
  const float* b_enc = (const float*)d_in[2];
  const float* W_dec = (const float*)d_in[3];
  const float* b_dec = (const float*)d_in[4];
  float* out = (float*)d_out;

  const size_t wb_bytes = (size_t)V * H * 2;       // 25.6 MB bf16 W_dec (packed)
  const size_t hid_bytes = (size_t)B * H * 2;      // 512 KB bf16 hidden
  const bool pre = ws_size >= wb_bytes + hid_bytes + (size_t)B * 4;

  unsigned short* Wb;
  unsigned short* hid;
  float* accum;
  if (pre) {
    Wb = (unsigned short*)d_ws;
    hid = (unsigned short*)((char*)d_ws + wb_bytes);
    accum = (float*)((char*)d_ws + wb_bytes + hid_bytes);
  } else {
    Wb = nullptr;
    hid = (unsigned short*)d_ws;
    accum = (float*)((char*)d_ws + hid_bytes);
  }

  const int castBlocks = pre ? NT : 0;
  prep_fused<<<dim3(castBlocks + PREPB), 256, 0, stream>>>(
      idx, W_enc, b_enc, W_dec, hid, accum, Wb, castBlocks);

  if (pre) {
    lse_pass<true><<<dim3(NSTRIP, NRG), 256, 0, stream>>>((const void*)Wb, hid, b_dec, accum);
    out_pass<true><<<dim3(NSTRIP, NRG), 256, 0, stream>>>((const void*)Wb, hid, b_dec, accum, out);
  } else {
    lse_pass<false><<<dim3(NSTRIP, NRG), 256, 0, stream>>>((const void*)W_dec, hid, b_dec, accum);
    out_pass<false><<<dim3(NSTRIP, NRG), 256, 0, stream>>>((const void*)W_dec, hid, b_dec, accum, out);
  }
}

// Round 16
// 271.243 us; speedup vs baseline: 1.0251x; 1.0251x over previous
//
#include <hip/hip_runtime.h>
#include <cstdint>
#include <cstddef>

#define V 100000
#define H 128
#define B 2048
#define NT 6250      // vocab tiles of 16 (V/16 exact)
#define CHUNK 26     // tiles per strip (even -> aligned 128B tile pairs)
#define NSTRIP 241   // 241*26 = 6266 >= 6250; last strip = 10 tiles (even)
#define NRG 8        // row-groups: 8 * 256 rows = 2048

typedef __attribute__((ext_vector_type(8))) short short8;
typedef __attribute__((ext_vector_type(4))) float f32x4;

static __device__ __forceinline__ unsigned short f2bf(float f) {
  unsigned int u = __builtin_bit_cast(unsigned int, f);
  u += 0x7fffu + ((u >> 16) & 1u);   // round-to-nearest-even
  return (unsigned short)(u >> 16);
}

// ---- prep 1: hidden[b][k] = W_enc[k][idx[b]] + b_enc[k]  (bf16), zero accum ----
__global__ void __launch_bounds__(256) prep_hidden(
    const int* __restrict__ idx, const float* __restrict__ W_enc,
    const float* __restrict__ b_enc, unsigned short* __restrict__ hid,
    float* __restrict__ accum) {
  int gid = blockIdx.x * 256 + threadIdx.x;
  if (gid < B) accum[gid] = 0.0f;
  if (gid >= B * H) return;
  int b = gid >> 7;
  int k = gid & (H - 1);
  float v = W_enc[(size_t)k * V + idx[b]] + b_enc[k];
  hid[gid] = f2bf(v);
}

// ---- prep 2: W_dec fp32 -> bf16, FRAGMENT-PACKED layout ----
// Wpk[t*2048 + s*512 + lane*8 + j] = bf16( W[(t*16 + (lane&15))*H + (lane>>4)*8 + s*32 + j] )
__global__ void __launch_bounds__(256) cast_wdec_packed(
    const float* __restrict__ W, unsigned short* __restrict__ Wpk) {
  const int t = blockIdx.x;                 // vocab tile
  const int s = threadIdx.x >> 6;           // k-slice 0..3
  const int lane = threadIdx.x & 63;
  const int l15 = lane & 15;
  const int q = lane >> 4;
  const float* p = W + (size_t)(t * 16 + l15) * H + q * 8 + s * 32;
  float4 x = *reinterpret_cast<const float4*>(p);
  float4 y = *reinterpret_cast<const float4*>(p + 4);
  short8 o;
  o[0] = (short)f2bf(x.x); o[1] = (short)f2bf(x.y);
  o[2] = (short)f2bf(x.z); o[3] = (short)f2bf(x.w);
  o[4] = (short)f2bf(y.x); o[5] = (short)f2bf(y.y);
  o[6] = (short)f2bf(y.z); o[7] = (short)f2bf(y.w);
  *reinterpret_cast<short8*>(Wpk + (size_t)t * 2048 + s * 512 + lane * 8) = o;
}

// ---- W-fragment loader: packed-bf16 path or fp32 scattered fallback ----
template <bool PRE>
static __device__ __forceinline__ short8 loadW(const void* Wv, int t, int s,
                                               int lane, int l15, int q) {
  if constexpr (PRE) {
    return *reinterpret_cast<const short8*>(
        reinterpret_cast<const unsigned short*>(Wv) +
        (size_t)t * 2048 + s * 512 + lane * 8);
  } else {
    const float* p = reinterpret_cast<const float*>(Wv) +
                     (size_t)(t * 16 + l15) * H + q * 8 + s * 32;
    float4 x = *reinterpret_cast<const float4*>(p);
    float4 y = *reinterpret_cast<const float4*>(p + 4);
    short8 o;
    o[0] = (short)f2bf(x.x); o[1] = (short)f2bf(x.y);
    o[2] = (short)f2bf(x.z); o[3] = (short)f2bf(x.w);
    o[4] = (short)f2bf(y.x); o[5] = (short)f2bf(y.y);
    o[6] = (short)f2bf(y.z); o[7] = (short)f2bf(y.w);
    return o;
  }
}

// SWAPPED operands: A = W fragment (vocab = M), B = hid fragment (batch = N).
// A/B in-layout: row|col = l15, k = q*8+j. D: row(vocab) = q*4+j, col(batch) = l15.

// ---- pass A (r9 body): per-row sum of exp(logit), depth-1 prefetch ----
template <bool PRE>
__global__ void __launch_bounds__(256) lse_pass(
    const void* __restrict__ Wv, const unsigned short* __restrict__ hid,
    const float* __restrict__ b_dec, float* __restrict__ accum) {
  const int lane = threadIdx.x & 63;
  const int wv = threadIdx.x >> 6;
  const int l15 = lane & 15;
  const int q = lane >> 4;
  const int rowbase = blockIdx.y * 256 + wv * 64;  // 64 batch rows per wave

  const unsigned short* ap = hid + (size_t)(rowbase + l15) * H + q * 8;
  short8 hf[4][4];
#pragma unroll
  for (int f = 0; f < 4; ++f)
#pragma unroll
    for (int s = 0; s < 4; ++s)
      hf[f][s] = *reinterpret_cast<const short8*>(ap + (size_t)f * 16 * H + s * 32);

  float ps[4] = {0.f, 0.f, 0.f, 0.f};

  const int t0 = blockIdx.x * CHUNK;
  const int t1 = (t0 + CHUNK < NT) ? t0 + CHUNK : NT;

  short8 wb[4];
#pragma unroll
  for (int s = 0; s < 4; ++s) wb[s] = loadW<PRE>(Wv, t0, s, lane, l15, q);
  float4 bd4 = *reinterpret_cast<const float4*>(b_dec + t0 * 16 + q * 4);

#pragma unroll 2
  for (int t = t0; t < t1; ++t) {
    const int tn = (t + 1 < t1) ? t + 1 : t;
    short8 wn[4];
#pragma unroll
    for (int s = 0; s < 4; ++s) wn[s] = loadW<PRE>(Wv, tn, s, lane, l15, q);
    float4 bdn = *reinterpret_cast<const float4*>(b_dec + tn * 16 + q * 4);

#pragma unroll
    for (int f = 0; f < 4; ++f) {
      f32x4 acc = {0.f, 0.f, 0.f, 0.f};
#pragma unroll
      for (int s = 0; s < 4; ++s)
        acc = __builtin_amdgcn_mfma_f32_16x16x32_bf16(wb[s], hf[f][s], acc, 0, 0, 0);
      ps[f] += __expf(acc[0] + bd4.x) + __expf(acc[1] + bd4.y) +
               __expf(acc[2] + bd4.z) + __expf(acc[3] + bd4.w);
    }
#pragma unroll
    for (int s = 0; s < 4; ++s) wb[s] = wn[s];
    bd4 = bdn;
  }

#pragma unroll
  for (int f = 0; f < 4; ++f) {
    ps[f] += __shfl_xor(ps[f], 16, 64);
    ps[f] += __shfl_xor(ps[f], 32, 64);
    if (q == 0) atomicAdd(&accum[rowbase + f * 16 + l15], ps[f]);
  }
}

// ---- pass B (r9 body): recompute logits, write out = logit + b_dec - lse.
// Tile-pair processing: two 64B halves of one 128B line stored back-to-back
// (plain stores) so L2 merges full lines. ----
template <bool PRE>
__global__ void __launch_bounds__(256) out_pass(
    const void* __restrict__ Wv, const unsigned short* __restrict__ hid,
    const float* __restrict__ b_dec, const float* __restrict__ accum,
    float* __restrict__ out) {
  const int lane = threadIdx.x & 63;
  const int wv = threadIdx.x >> 6;
  const int l15 = lane & 15;
  const int q = lane >> 4;
  const int rowbase = blockIdx.y * 256 + wv * 64;

  const unsigned short* ap = hid + (size_t)(rowbase + l15) * H + q * 8;
  short8 hf[4][4];
#pragma unroll
  for (int f = 0; f < 4; ++f)
#pragma unroll
    for (int s = 0; s < 4; ++s)
      hf[f][s] = *reinterpret_cast<const short8*>(ap + (size_t)f * 16 * H + s * 32);

  const int t0 = blockIdx.x * CHUNK;   // even -> (t0, t0+1) is a 128B line pair
  const int t1 = (t0 + CHUNK < NT) ? t0 + CHUNK : NT;
  const int NPAIR = (t1 - t0) >> 1;    // even counts everywhere

  float ls[4];
  size_t optr[4];
#pragma unroll
  for (int f = 0; f < 4; ++f) {
    ls[f] = __logf(accum[rowbase + f * 16 + l15]);
    optr[f] = (size_t)(rowbase + f * 16 + l15) * V + (size_t)t0 * 16 + q * 4;
  }

  // current pair fragments (a = even tile, b = odd tile)
  short8 wa[4], wbv[4];
#pragma unroll
  for (int s = 0; s < 4; ++s) {
    wa[s] = loadW<PRE>(Wv, t0, s, lane, l15, q);
    wbv[s] = loadW<PRE>(Wv, t0 + 1, s, lane, l15, q);
  }
  float4 bda = *reinterpret_cast<const float4*>(b_dec + t0 * 16 + q * 4);
  float4 bdb = *reinterpret_cast<const float4*>(b_dec + (t0 + 1) * 16 + q * 4);

  for (int tp = 0; tp < NPAIR; ++tp) {
    // prefetch next pair
    const int tpn = (tp + 1 < NPAIR) ? tp + 1 : tp;
    const int ta = t0 + 2 * tpn;
    short8 na[4], nb[4];
#pragma unroll
    for (int s = 0; s < 4; ++s) {
      na[s] = loadW<PRE>(Wv, ta, s, lane, l15, q);
      nb[s] = loadW<PRE>(Wv, ta + 1, s, lane, l15, q);
    }
    const float4 bna = *reinterpret_cast<const float4*>(b_dec + ta * 16 + q * 4);
    const float4 bnb = *reinterpret_cast<const float4*>(b_dec + (ta + 1) * 16 + q * 4);

#pragma unroll
    for (int f = 0; f < 4; ++f) {
      f32x4 acc0 = {0.f, 0.f, 0.f, 0.f};
      f32x4 acc1 = {0.f, 0.f, 0.f, 0.f};
#pragma unroll
      for (int s = 0; s < 4; ++s) {
        acc0 = __builtin_amdgcn_mfma_f32_16x16x32_bf16(wa[s], hf[f][s], acc0, 0, 0, 0);
        acc1 = __builtin_amdgcn_mfma_f32_16x16x32_bf16(wbv[s], hf[f][s], acc1, 0, 0, 0);
      }
      f32x4 o0, o1;
      o0[0] = acc0[0] + bda.x - ls[f];
      o0[1] = acc0[1] + bda.y - ls[f];
      o0[2] = acc0[2] + bda.z - ls[f];
      o0[3] = acc0[3] + bda.w - ls[f];
      o1[0] = acc1[0] + bdb.x - ls[f];
      o1[1] = acc1[1] + bdb.y - ls[f];
      o1[2] = acc1[2] + bdb.z - ls[f];
      o1[3] = acc1[3] + bdb.w - ls[f];
      // two halves of the same 128B line, issued back-to-back; plain stores
      float* p = out + optr[f];
      *reinterpret_cast<f32x4*>(p) = o0;
      *reinterpret_cast<f32x4*>(p + 16) = o1;
      optr[f] += 32;
    }
#pragma unroll
    for (int s = 0; s < 4; ++s) { wa[s] = na[s]; wbv[s] = nb[s]; }
    bda = bna;
    bdb = bnb;
  }
}

extern "C" void kernel_launch(void* const* d_in, const int* in_sizes, int n_in,
                              void* d_out, int out_size, void* d_ws, size_t ws_size,
                              hipStream_t stream) {
  const int* idx = (const int*)d_in[0];
  const float* W_enc = (const float*)d_in[1];
  const float* b_enc = (const float*)d_in[2];
  const float* W_dec = (const float*)d_in[3];
  const float* b_dec = (const float*)d_in[4];
  float* out = (float*)d_out;

  const size_t wb_bytes = (size_t)V * H * 2;       // 25.6 MB bf16 W_dec (packed)
  const size_t hid_bytes = (size_t)B * H * 2;      // 512 KB bf16 hidden
  const bool pre = ws_size >= wb_bytes + hid_bytes + (size_t)B * 4;

  unsigned short* Wb;
  unsigned short* hid;
  float* accum;
  if (pre) {
    Wb = (unsigned short*)d_ws;
    hid = (unsigned short*)((char*)d_ws + wb_bytes);
    accum = (float*)((char*)d_ws + wb_bytes + hid_bytes);
  } else {
    Wb = nullptr;
    hid = (unsigned short*)d_ws;
    accum = (float*)((char*)d_ws + hid_bytes);
  }

  prep_hidden<<<dim3((B * H + 255) / 256), 256, 0, stream>>>(idx, W_enc, b_enc, hid, accum);

  if (pre) {
    cast_wdec_packed<<<dim3(NT), 256, 0, stream>>>(W_dec, Wb);
    lse_pass<true><<<dim3(NSTRIP, NRG), 256, 0, stream>>>((const void*)Wb, hid, b_dec, accum);
    out_pass<true><<<dim3(NSTRIP, NRG), 256, 0, stream>>>((const void*)Wb, hid, b_dec, accum, out);
  } else {
    lse_pass<false><<<dim3(NSTRIP, NRG), 256, 0, stream>>>((const void*)W_dec, hid, b_dec, accum);
    out_pass<false><<<dim3(NSTRIP, NRG), 256, 0, stream>>>((const void*)W_dec, hid, b_dec, accum, out);
  }
}